// Round 3
// baseline (295.062 us; speedup 1.0000x reference)
//
#include <hip/hip_runtime.h>
#include <hip/hip_bf16.h>

typedef short v8s __attribute__((ext_vector_type(8)));
typedef float f32x4 __attribute__((ext_vector_type(4)));
typedef unsigned short u16;
typedef unsigned int u32;

#define HW_   3136      // 56*56
#define W_    56
#define PW_   58
#define CIN_  128
#define COUT_ 256
#define NB_   32
#define KCNT  100352.0f // 32*56*56

// xp: NHWC padded bf16 [32][58][58][128]
#define XP_ELEMS (NB_*PW_*PW_*CIN_)      // 13,778,944
#define WT_ELEMS (9*COUT_*CIN_)          // 294,912
#define WT_OFFB  (XP_ELEMS*2)
#define ST_OFFB  (WT_OFFB + WT_ELEMS*2)

#define GLOAD16(g, l) __builtin_amdgcn_global_load_lds( \
    (const __attribute__((address_space(1))) u32*)(g), \
    (__attribute__((address_space(3))) u32*)(l), 16, 0, 0)

// ---------------- pad + transpose: x (32,128,56,56) f32 -> xp (32,58,58,128) bf16 ----------------
extern "C" __global__ void __launch_bounds__(256)
pad_kernel(const float* __restrict__ x, u16* __restrict__ xp)
{
    const int b  = blockIdx.x;          // 32*58 blocks: (n, hp)
    const int n  = b / PW_;
    const int hp = b - n * PW_;
    u16* rowp = xp + (n * PW_ + hp) * PW_ * CIN_;
    const int tid = threadIdx.x;

    if (hp == 0 || hp == PW_ - 1) {
        #pragma unroll
        for (int k = 0; k < 4; ++k) {
            const int j = tid + k * 256;
            if (j < PW_ * CIN_ / 8)
                *(v8s*)&rowp[j * 8] = (v8s){0,0,0,0,0,0,0,0};
        }
        return;
    }

    __shared__ float tile[CIN_ * 58];   // [c][w], stride 58 (2-way-free on strided reads)
    const float* xrow = x + n * CIN_ * HW_ + (hp - 1) * W_;
    for (int idx = tid; idx < CIN_ * 14; idx += 256) {    // 1792 float4 loads
        const int c  = idx / 14;
        const int w4 = idx - c * 14;
        const float4 v = *(const float4*)&xrow[c * HW_ + w4 * 4];
        float* tp = &tile[c * 58 + w4 * 4];
        tp[0] = v.x; tp[1] = v.y; tp[2] = v.z; tp[3] = v.w;
    }
    __syncthreads();

    if (tid < 32) {                     // wp=0 and wp=57 borders
        const int wp = (tid >> 4) * (PW_ - 1);
        const int cg = tid & 15;
        *(v8s*)&rowp[wp * CIN_ + cg * 8] = (v8s){0,0,0,0,0,0,0,0};
    }
    for (int idx = tid; idx < W_ * 16; idx += 256) {      // 896 v8s chunks
        const int wp = (idx >> 4) + 1;
        const int cg = idx & 15;
        v8s v;
        #pragma unroll
        for (int j = 0; j < 8; ++j) {
            __hip_bfloat16 bv = __float2bfloat16(tile[(cg * 8 + j) * 58 + (wp - 1)]);
            v[j] = *(short*)&bv;
        }
        *(v8s*)&rowp[wp * CIN_ + cg * 8] = v;
    }
}

// ---------------- weight transform: wgt (Cout,Cin,3,3) f32 -> wt[tap][cout][cin] bf16 ----------------
extern "C" __global__ void wt_kernel(const float* __restrict__ wgt, u16* __restrict__ wt)
{
    const int e   = blockIdx.x * 256 + threadIdx.x;  // 294912 -> 1152 blocks
    const int ci  = e & 127;
    const int t2  = e >> 7;
    const int co  = t2 & 255;
    const int tap = t2 >> 8;
    __hip_bfloat16 b = __float2bfloat16(wgt[co * 1152 + ci * 9 + tap]);
    wt[e] = *(u16*)&b;
}

// ================= conv: implicit GEMM, 128x256 tile, BK=64, triple-buffer + counted vmcnt =======
#define MFMA4(MF_A, B_, N_) \
    acc[0][N_] = __builtin_amdgcn_mfma_f32_16x16x32_bf16(a0, B_, acc[0][N_], 0, 0, 0); \
    acc[1][N_] = __builtin_amdgcn_mfma_f32_16x16x32_bf16(a1, B_, acc[1][N_], 0, 0, 0); \
    acc[2][N_] = __builtin_amdgcn_mfma_f32_16x16x32_bf16(a2, B_, acc[2][N_], 0, 0, 0); \
    acc[3][N_] = __builtin_amdgcn_mfma_f32_16x16x32_bf16(a3, B_, acc[3][N_], 0, 0, 0);

#define PHASE_MID() \
    __builtin_amdgcn_s_barrier(); \
    asm volatile("s_waitcnt lgkmcnt(0)" ::: "memory"); \
    __builtin_amdgcn_sched_barrier(0); \
    __builtin_amdgcn_s_setprio(1);

#define PHASE_END() \
    __builtin_amdgcn_s_setprio(0); \
    __builtin_amdgcn_s_barrier();

#define CONV_ITER(KT, C0, C2, VM, PF)                                          \
{                                                                              \
    int xoff2 = 0, woff2 = 0;                                                  \
    if (PF) {                                                                  \
        const int ktp = (KT) + 2;                                              \
        const int tap = ktp >> 1;                                              \
        const int kh  = (tap * 11) >> 5;                                       \
        const int kw  = tap - kh * 3;                                          \
        const int cb  = (ktp & 1) << 6;                                        \
        xoff2 = (kh * PW_ + kw) * CIN_ + cb;                                   \
        woff2 = tap * (COUT_ * CIN_) + cb;                                     \
    }                                                                          \
    const u16* acur = As + (C0) * 8192;                                        \
    const u16* bcur = Bs + (C0) * 16384;                                       \
    u16* apre = As + (C2) * 8192;                                              \
    u16* bpre = Bs + (C2) * 16384;                                             \
    asm volatile("s_waitcnt vmcnt(" #VM ")" ::: "memory");                     \
    __builtin_amdgcn_s_barrier();                                              \
    /* ---- phase 0: A prefetch | A ks0 + B nf0/1 ks0 | 8 MFMA ---- */         \
    if (PF) {                                                                  \
        GLOAD16(xp + xa0 + xoff2, apre + wid * 512);                           \
        GLOAD16(xp + xa1 + xoff2, apre + (8 + wid) * 512);                     \
    }                                                                          \
    a0 = *(const v8s*)(acur + ar0 + ck0);                                      \
    a1 = *(const v8s*)(acur + ar1 + ck0);                                      \
    a2 = *(const v8s*)(acur + ar2 + ck0);                                      \
    a3 = *(const v8s*)(acur + ar3 + ck0);                                      \
    b0 = *(const v8s*)(bcur + br0 + ck0);                                      \
    b1 = *(const v8s*)(bcur + br1 + ck0);                                      \
    PHASE_MID();                                                               \
    MFMA4(a, b0, 0); MFMA4(a, b1, 1);                                          \
    PHASE_END();                                                               \
    /* ---- phase 1: B prefetch 0/1 | B nf2/3 ks0 | 8 MFMA ---- */             \
    if (PF) {                                                                  \
        GLOAD16(wt + wb0 + woff2, bpre + wid * 512);                           \
        GLOAD16(wt + wb1 + woff2, bpre + (8 + wid) * 512);                     \
    }                                                                          \
    b2 = *(const v8s*)(bcur + br2 + ck0);                                      \
    b3 = *(const v8s*)(bcur + br3 + ck0);                                      \
    PHASE_MID();                                                               \
    MFMA4(a, b2, 2); MFMA4(a, b3, 3);                                          \
    PHASE_END();                                                               \
    /* ---- phase 2: B prefetch 2/3 | A ks1 + B nf0/1 ks1 | 8 MFMA ---- */     \
    if (PF) {                                                                  \
        GLOAD16(wt + wb2 + woff2, bpre + (16 + wid) * 512);                    \
        GLOAD16(wt + wb3 + woff2, bpre + (24 + wid) * 512);                    \
    }                                                                          \
    a0 = *(const v8s*)(acur + ar0 + ck1);                                      \
    a1 = *(const v8s*)(acur + ar1 + ck1);                                      \
    a2 = *(const v8s*)(acur + ar2 + ck1);                                      \
    a3 = *(const v8s*)(acur + ar3 + ck1);                                      \
    b0 = *(const v8s*)(bcur + br0 + ck1);                                      \
    b1 = *(const v8s*)(bcur + br1 + ck1);                                      \
    PHASE_MID();                                                               \
    MFMA4(a, b0, 0); MFMA4(a, b1, 1);                                          \
    PHASE_END();                                                               \
    /* ---- phase 3: B nf2/3 ks1 | 8 MFMA ---- */                              \
    b2 = *(const v8s*)(bcur + br2 + ck1);                                      \
    b3 = *(const v8s*)(bcur + br3 + ck1);                                      \
    PHASE_MID();                                                               \
    MFMA4(a, b2, 2); MFMA4(a, b3, 3);                                          \
    PHASE_END();                                                               \
}

extern "C" __global__ void __launch_bounds__(512)
conv_kernel(const u16* __restrict__ xp, const u16* __restrict__ wt,
            const float* __restrict__ bias, float* __restrict__ out,
            float* __restrict__ stats)
{
    __shared__ u16 As[3 * 128 * 64];   // 48 KB
    __shared__ u16 Bs[3 * 256 * 64];   // 96 KB

    const int t    = threadIdx.x;
    const int lane = t & 63;
    const int wid  = t >> 6;

    // XCD-bijective remap: 784 blocks = 8 XCD chunks x 98
    const int bid   = blockIdx.x;
    const int mbase = ((bid & 7) * 98 + (bid >> 3)) << 7;

    // staging geometry (verified swizzle involution from R2)
    const int srow8 = lane >> 3;                 // == (staged LDS row) & 7
    const int swz   = ((lane & 7) ^ srow8) << 3; // pre-swizzled source chunk
    int xa0, xa1, wb0, wb1, wb2, wb3;
    {
        #pragma unroll
        for (int j = 0; j < 2; ++j) {
            const int r  = (j * 8 + wid) * 8 + srow8;   // 0..127
            const int m  = mbase + r;
            const int n0 = m / HW_;
            const int hw0 = m - n0 * HW_;
            const int h0 = hw0 / W_;
            const int w0 = hw0 - h0 * W_;
            const int a  = ((n0 * PW_ + h0) * PW_ + w0) * CIN_ + swz;
            if (j == 0) xa0 = a; else xa1 = a;
        }
        #pragma unroll
        for (int i = 0; i < 4; ++i) {
            const int r = (i * 8 + wid) * 8 + srow8;    // 0..255 (cout)
            const int a = r * CIN_ + swz;
            if (i == 0) wb0 = a; else if (i == 1) wb1 = a;
            else if (i == 2) wb2 = a; else wb3 = a;
        }
    }

    // fragment-read geometry
    const int wr = wid >> 2, wc = wid & 3;       // 2M x 4N waves, 64x64 each
    const int frow = lane & 15;
    const int kg   = lane >> 4;
    const int ck0  = ((kg)     ^ (frow & 7)) << 3;
    const int ck1  = ((4 | kg) ^ (frow & 7)) << 3;
    const int ar0 = (wr * 64 +  0 + frow) * 64;
    const int ar1 = (wr * 64 + 16 + frow) * 64;
    const int ar2 = (wr * 64 + 32 + frow) * 64;
    const int ar3 = (wr * 64 + 48 + frow) * 64;
    const int br0 = (wc * 64 +  0 + frow) * 64;
    const int br1 = (wc * 64 + 16 + frow) * 64;
    const int br2 = (wc * 64 + 32 + frow) * 64;
    const int br3 = (wc * 64 + 48 + frow) * 64;

    f32x4 acc[4][4];
    #pragma unroll
    for (int i = 0; i < 4; ++i)
        #pragma unroll
        for (int j = 0; j < 4; ++j) acc[i][j] = (f32x4){0.f, 0.f, 0.f, 0.f};
    v8s a0, a1, a2, a3, b0, b1, b2, b3;

    // prologue: stage kt=0 -> buf0, kt=1 -> buf1 (tap0, cinb 0/64)
    GLOAD16(xp + xa0,      As + wid * 512);
    GLOAD16(xp + xa1,      As + (8 + wid) * 512);
    GLOAD16(wt + wb0,      Bs + wid * 512);
    GLOAD16(wt + wb1,      Bs + (8 + wid) * 512);
    GLOAD16(wt + wb2,      Bs + (16 + wid) * 512);
    GLOAD16(wt + wb3,      Bs + (24 + wid) * 512);
    GLOAD16(xp + xa0 + 64, As + 8192  + wid * 512);
    GLOAD16(xp + xa1 + 64, As + 8192  + (8 + wid) * 512);
    GLOAD16(wt + wb0 + 64, Bs + 16384 + wid * 512);
    GLOAD16(wt + wb1 + 64, Bs + 16384 + (8 + wid) * 512);
    GLOAD16(wt + wb2 + 64, Bs + 16384 + (16 + wid) * 512);
    GLOAD16(wt + wb3 + 64, Bs + 16384 + (24 + wid) * 512);

    #pragma unroll 1
    for (int g = 0; g < 5; ++g) {                 // kt = 0..14
        const int kt = g * 3;
        CONV_ITER(kt,     0, 2, 6, 1);
        CONV_ITER(kt + 1, 1, 0, 6, 1);
        CONV_ITER(kt + 2, 2, 1, 6, 1);
    }
    CONV_ITER(15, 0, 2, 6, 1);                    // stages kt=17
    CONV_ITER(16, 1, 0, 6, 0);
    CONV_ITER(17, 2, 1, 0, 0);

    // epilogue: bias + store fp32 NCHW + fused channel sum/sumsq (verified layout)
    const int lgrp = lane >> 4;
    #pragma unroll
    for (int nf = 0; nf < 4; ++nf) {
        const int co = wc * 64 + nf * 16 + frow;       // C/D col = lane&15
        const float bv = bias[co];
        float s = 0.f, q = 0.f;
        #pragma unroll
        for (int mf = 0; mf < 4; ++mf) {
            const int mloc = wr * 64 + mf * 16 + lgrp * 4;  // C/D row = (lane>>4)*4+i
            const int mg2  = mbase + mloc;
            const int n2   = mg2 / HW_;
            const int hw2  = mg2 - n2 * HW_;
            float4 ov; float vx;
            vx = acc[mf][nf][0] + bv; ov.x = vx; s += vx; q += vx * vx;
            vx = acc[mf][nf][1] + bv; ov.y = vx; s += vx; q += vx * vx;
            vx = acc[mf][nf][2] + bv; ov.z = vx; s += vx; q += vx * vx;
            vx = acc[mf][nf][3] + bv; ov.w = vx; s += vx; q += vx * vx;
            *(float4*)(out + (n2 * COUT_ + co) * HW_ + hw2) = ov;
        }
        s += __shfl_xor(s, 16); s += __shfl_xor(s, 32);
        q += __shfl_xor(q, 16); q += __shfl_xor(q, 32);
        if (lgrp == 0) {
            atomicAdd(&stats[co], s);
            atomicAdd(&stats[COUT_ + co], q);
        }
    }
}

// ---------------- BN(training) + ReLU, in place on d_out ----------------
extern "C" __global__ void bn_kernel(float* __restrict__ y, const float* __restrict__ stats,
                                     const float* __restrict__ gamma, const float* __restrict__ beta)
{
    const int i4 = blockIdx.x * 256 + threadIdx.x;
    const int e  = i4 * 4;
    const int co = (e / HW_) & (COUT_ - 1);
    const float inv  = 1.f / KCNT;
    const float mean = stats[co] * inv;
    const float var  = stats[COUT_ + co] * inv - mean * mean;
    const float scale = gamma[co] * rsqrtf(var + 1e-5f);
    const float shift = beta[co] - mean * scale;
    float4 v = *(float4*)(y + e);
    v.x = fmaxf(fmaf(v.x, scale, shift), 0.f);
    v.y = fmaxf(fmaf(v.y, scale, shift), 0.f);
    v.z = fmaxf(fmaf(v.z, scale, shift), 0.f);
    v.w = fmaxf(fmaf(v.w, scale, shift), 0.f);
    *(float4*)(y + e) = v;
}

extern "C" void kernel_launch(void* const* d_in, const int* in_sizes, int n_in,
                              void* d_out, int out_size, void* d_ws, size_t ws_size,
                              hipStream_t stream)
{
    const float* x     = (const float*)d_in[0];
    const float* wgt   = (const float*)d_in[1];
    const float* bias  = (const float*)d_in[2];
    const float* gamma = (const float*)d_in[3];
    const float* beta  = (const float*)d_in[4];
    float* out = (float*)d_out;

    char* ws = (char*)d_ws;
    u16*   xp    = (u16*)ws;
    u16*   wt    = (u16*)(ws + WT_OFFB);
    float* stats = (float*)(ws + ST_OFFB);

    hipMemsetAsync(stats, 0, 2 * COUT_ * sizeof(float), stream);

    pad_kernel<<<NB_ * PW_, 256, 0, stream>>>(x, xp);                 // 1856 blocks
    wt_kernel<<<WT_ELEMS / 256, 256, 0, stream>>>(wgt, wt);           // 1152 blocks
    conv_kernel<<<784, 512, 0, stream>>>(xp, wt, bias, out, stats);
    bn_kernel<<<(out_size / 4) / 256, 256, 0, stream>>>(out, stats, gamma, beta);
}

// Round 4
// 273.680 us; speedup vs baseline: 1.0781x; 1.0781x over previous
//
#include <hip/hip_runtime.h>
#include <hip/hip_bf16.h>

typedef short v8s __attribute__((ext_vector_type(8)));
typedef float f32x4 __attribute__((ext_vector_type(4)));
typedef unsigned short u16;
typedef unsigned int u32;

#define HW_   3136      // 56*56
#define W_    56
#define PW_   58
#define CIN_  128
#define COUT_ 256
#define NB_   32
#define KCNT  100352.0f // 32*56*56

// xp: NHWC padded bf16 [32][58][58][128]
#define XP_ELEMS (NB_*PW_*PW_*CIN_)      // 13,778,944
#define WT_ELEMS (9*COUT_*CIN_)          // 294,912
#define WT_OFFB  (XP_ELEMS*2)
#define ST_OFFB  (WT_OFFB + WT_ELEMS*2)

#define PAD_BLOCKS (NB_*PW_)             // 1856
#define WT_BLOCKS  (WT_ELEMS/256)        // 1152

#define GLOAD16(g, l) __builtin_amdgcn_global_load_lds( \
    (const __attribute__((address_space(1))) u32*)(g), \
    (__attribute__((address_space(3))) u32*)(l), 16, 0, 0)

// ---------- fused pre: pad/transpose x -> NHWC bf16, weight transform, stats zero ----------
extern "C" __global__ void __launch_bounds__(256)
pre_kernel(const float* __restrict__ x, const float* __restrict__ wgt,
           u16* __restrict__ xp, u16* __restrict__ wt, float* __restrict__ stats)
{
    const int b   = blockIdx.x;
    const int tid = threadIdx.x;

    if (b >= PAD_BLOCKS) {
        // ---- weight transform: wgt (Cout,Cin,3,3) f32 -> wt[tap][cout][cin] bf16 ----
        const int e   = (b - PAD_BLOCKS) * 256 + tid;
        const int ci  = e & 127;
        const int t2  = e >> 7;
        const int co  = t2 & 255;
        const int tap = t2 >> 8;
        __hip_bfloat16 bv = __float2bfloat16(wgt[co * 1152 + ci * 9 + tap]);
        wt[e] = *(u16*)&bv;
        if (b == PAD_BLOCKS) {          // zero the stats buffer (ws is poisoned each call)
            stats[tid] = 0.f;
            stats[tid + 256] = 0.f;
        }
        return;
    }

    // ---- pad + transpose one (n, hp) row ----
    const int n  = b / PW_;
    const int hp = b - n * PW_;
    u16* rowp = xp + (n * PW_ + hp) * PW_ * CIN_;

    if (hp == 0 || hp == PW_ - 1) {
        #pragma unroll
        for (int k = 0; k < 4; ++k) {
            const int j = tid + k * 256;
            if (j < PW_ * CIN_ / 8)
                *(v8s*)&rowp[j * 8] = (v8s){0,0,0,0,0,0,0,0};
        }
        return;
    }

    __shared__ float tile[CIN_ * 58];   // [c][w], stride 58
    const float* xrow = x + n * CIN_ * HW_ + (hp - 1) * W_;
    for (int idx = tid; idx < CIN_ * 14; idx += 256) {    // float4 coalesced loads
        const int c  = idx / 14;
        const int w4 = idx - c * 14;
        const float4 v = *(const float4*)&xrow[c * HW_ + w4 * 4];
        float* tp = &tile[c * 58 + w4 * 4];
        tp[0] = v.x; tp[1] = v.y; tp[2] = v.z; tp[3] = v.w;
    }
    __syncthreads();

    if (tid < 32) {                     // wp=0 and wp=57 borders
        const int wp = (tid >> 4) * (PW_ - 1);
        const int cg = tid & 15;
        *(v8s*)&rowp[wp * CIN_ + cg * 8] = (v8s){0,0,0,0,0,0,0,0};
    }
    for (int idx = tid; idx < W_ * 16; idx += 256) {      // 896 v8s chunks
        const int wp = (idx >> 4) + 1;
        const int cg = idx & 15;
        v8s v;
        #pragma unroll
        for (int j = 0; j < 8; ++j) {
            __hip_bfloat16 bv = __float2bfloat16(tile[(cg * 8 + j) * 58 + (wp - 1)]);
            v[j] = *(short*)&bv;
        }
        *(v8s*)&rowp[wp * CIN_ + cg * 8] = v;
    }
}

// ====== conv: implicit GEMM 128x128, BK=64, double-buffer, stage-early + 1 barrier/K-tile ======
extern "C" __global__ void __launch_bounds__(256)
conv_kernel(const u16* __restrict__ xp, const u16* __restrict__ wt,
            const float* __restrict__ bias, float* __restrict__ out,
            float* __restrict__ stats)
{
    __shared__ u16 As[2 * 128 * 64];   // 32 KB
    __shared__ u16 Bs[2 * 128 * 64];   // 32 KB  (64 KB total -> 2 blocks/CU)

    const int t    = threadIdx.x;
    const int lane = t & 63;
    const int wid  = t >> 6;

    // XCD-bijective remap: 1568 blocks = 8 chunks x 196; pairs (2j,2j+1) share the A-tile
    const int bid     = blockIdx.x;
    const int logical = (bid & 7) * 196 + (bid >> 3);
    const int cbase   = (logical & 1) << 7;
    const int mbase   = (logical >> 1) << 7;

    // staging geometry (R2-verified swizzle involution)
    const int srow8 = lane >> 3;                 // == (staged LDS row) & 7
    const int swz   = ((lane & 7) ^ srow8) << 3; // pre-swizzled source chunk
    int xa[4], wb[4];
    #pragma unroll
    for (int i = 0; i < 4; ++i) {
        const int r   = wid * 32 + i * 8 + srow8;
        const int m   = mbase + r;
        const int n0  = m / HW_;
        const int hw0 = m - n0 * HW_;
        const int h0  = hw0 / W_;
        const int w0  = hw0 - h0 * W_;
        xa[i] = ((n0 * PW_ + h0) * PW_ + w0) * CIN_ + swz;
        wb[i] = (cbase + r) * CIN_ + swz;
    }

    f32x4 acc[4][4];
    #pragma unroll
    for (int i = 0; i < 4; ++i)
        #pragma unroll
        for (int j = 0; j < 4; ++j) acc[i][j] = (f32x4){0.f, 0.f, 0.f, 0.f};

    const int wr = wid >> 1, wc = wid & 1;   // 2x2 wave grid, 64x64 each
    const int frow = lane & 15;
    const int kg   = lane >> 4;

    // prologue: stage kt=0 into buf0
    #pragma unroll
    for (int i = 0; i < 4; ++i) {
        GLOAD16(xp + xa[i], As + (wid * 32 + i * 8) * 64);
        GLOAD16(wt + wb[i], Bs + (wid * 32 + i * 8) * 64);
    }
    __syncthreads();   // compiler drains vmcnt(0): buf0 ready

    #pragma unroll 1
    for (int kt = 0; kt < 18; ++kt) {
        const int cur = kt & 1;
        const u16* acur = As + cur * 8192;
        const u16* bcur = Bs + cur * 8192;

        // ---- stage kt+1 into buf^1 FIRST (loads fly across the whole MFMA phase) ----
        if (kt < 17) {
            const int ktn  = kt + 1;
            const int tap  = ktn >> 1;
            const int kh   = (tap * 11) >> 5;           // tap/3 for tap in [0,9)
            const int kw   = tap - kh * 3;
            const int xoff = (kh * PW_ + kw) * CIN_ + ((ktn & 1) << 6);
            const int woff = tap * (COUT_ * CIN_) + ((ktn & 1) << 6);
            u16* apre = As + (cur ^ 1) * 8192;
            u16* bpre = Bs + (cur ^ 1) * 8192;
            #pragma unroll
            for (int i = 0; i < 4; ++i) {
                GLOAD16(xp + xa[i] + xoff, apre + (wid * 32 + i * 8) * 64);
                GLOAD16(wt + wb[i] + woff, bpre + (wid * 32 + i * 8) * 64);
            }
        }

        // ---- compute current K-tile: 2 k-slices x 16 MFMA ----
        #pragma unroll
        for (int ks = 0; ks < 2; ++ks) {
            const int ck = (((ks << 2) | kg) ^ (frow & 7)) << 3;
            v8s af[4], bf4[4];
            #pragma unroll
            for (int mf = 0; mf < 4; ++mf)
                af[mf] = *(const v8s*)(acur + (wr * 64 + mf * 16 + frow) * 64 + ck);
            #pragma unroll
            for (int nf = 0; nf < 4; ++nf)
                bf4[nf] = *(const v8s*)(bcur + (wc * 64 + nf * 16 + frow) * 64 + ck);
            #pragma unroll
            for (int mf = 0; mf < 4; ++mf)
                #pragma unroll
                for (int nf = 0; nf < 4; ++nf)
                    acc[mf][nf] = __builtin_amdgcn_mfma_f32_16x16x32_bf16(
                        af[mf], bf4[nf], acc[mf][nf], 0, 0, 0);
        }

        __syncthreads();   // drains vmcnt(0) (kt+1 loads landed) + guards buf reuse
    }

    // epilogue: bias + store fp32 NCHW + fused channel sum/sumsq (verified layout)
    const int lgrp = lane >> 4;
    #pragma unroll
    for (int nf = 0; nf < 4; ++nf) {
        const int co = cbase + wc * 64 + nf * 16 + frow;   // C/D col = lane&15
        const float bv = bias[co];
        float s = 0.f, q = 0.f;
        #pragma unroll
        for (int mf = 0; mf < 4; ++mf) {
            const int mloc = wr * 64 + mf * 16 + lgrp * 4; // C/D row = (lane>>4)*4+i
            const int mg2  = mbase + mloc;
            const int n2   = mg2 / HW_;
            const int hw2  = mg2 - n2 * HW_;
            float4 ov; float vx;
            vx = acc[mf][nf][0] + bv; ov.x = vx; s += vx; q += vx * vx;
            vx = acc[mf][nf][1] + bv; ov.y = vx; s += vx; q += vx * vx;
            vx = acc[mf][nf][2] + bv; ov.z = vx; s += vx; q += vx * vx;
            vx = acc[mf][nf][3] + bv; ov.w = vx; s += vx; q += vx * vx;
            *(float4*)(out + (n2 * COUT_ + co) * HW_ + hw2) = ov;
        }
        s += __shfl_xor(s, 16); s += __shfl_xor(s, 32);
        q += __shfl_xor(q, 16); q += __shfl_xor(q, 32);
        if (lgrp == 0) {
            atomicAdd(&stats[co], s);
            atomicAdd(&stats[COUT_ + co], q);
        }
    }
}

// ---------------- BN(training) + ReLU, in place on d_out ----------------
extern "C" __global__ void bn_kernel(float* __restrict__ y, const float* __restrict__ stats,
                                     const float* __restrict__ gamma, const float* __restrict__ beta)
{
    const int i4 = blockIdx.x * 256 + threadIdx.x;
    const int e  = i4 * 4;
    const int co = (e / HW_) & (COUT_ - 1);
    const float inv  = 1.f / KCNT;
    const float mean = stats[co] * inv;
    const float var  = stats[COUT_ + co] * inv - mean * mean;
    const float scale = gamma[co] * rsqrtf(var + 1e-5f);
    const float shift = beta[co] - mean * scale;
    float4 v = *(float4*)(y + e);
    v.x = fmaxf(fmaf(v.x, scale, shift), 0.f);
    v.y = fmaxf(fmaf(v.y, scale, shift), 0.f);
    v.z = fmaxf(fmaf(v.z, scale, shift), 0.f);
    v.w = fmaxf(fmaf(v.w, scale, shift), 0.f);
    *(float4*)(y + e) = v;
}

extern "C" void kernel_launch(void* const* d_in, const int* in_sizes, int n_in,
                              void* d_out, int out_size, void* d_ws, size_t ws_size,
                              hipStream_t stream)
{
    const float* x     = (const float*)d_in[0];
    const float* wgt   = (const float*)d_in[1];
    const float* bias  = (const float*)d_in[2];
    const float* gamma = (const float*)d_in[3];
    const float* beta  = (const float*)d_in[4];
    float* out = (float*)d_out;

    char* ws = (char*)d_ws;
    u16*   xp    = (u16*)ws;
    u16*   wt    = (u16*)(ws + WT_OFFB);
    float* stats = (float*)(ws + ST_OFFB);

    pre_kernel<<<PAD_BLOCKS + WT_BLOCKS, 256, 0, stream>>>(x, wgt, xp, wt, stats);
    conv_kernel<<<1568, 256, 0, stream>>>(xp, wt, bias, out, stats);
    bn_kernel<<<(out_size / 4) / 256, 256, 0, stream>>>(out, stats, gamma, beta);
}

// Round 5
// 259.931 us; speedup vs baseline: 1.1352x; 1.0529x over previous
//
#include <hip/hip_runtime.h>
#include <hip/hip_bf16.h>

typedef short v8s __attribute__((ext_vector_type(8)));
typedef float f32x4 __attribute__((ext_vector_type(4)));
typedef unsigned short u16;
typedef unsigned int u32;

#define HW_   3136      // 56*56
#define W_    56
#define PW_   58
#define CIN_  128
#define COUT_ 256
#define NB_   32
#define KCNT  100352.0f // 32*56*56

// xp: NHWC padded bf16 [32][58][58][128]
#define XP_ELEMS (NB_*PW_*PW_*CIN_)      // 13,778,944
#define WT_ELEMS (9*COUT_*CIN_)          // 294,912
#define WT_OFFB  (XP_ELEMS*2)
#define ST_OFFB  (WT_OFFB + WT_ELEMS*2)

#define PAD_BLOCKS (NB_*PW_)             // 1856
#define WT_BLOCKS  (WT_ELEMS/256)        // 1152

#define GLOAD16(g, l) __builtin_amdgcn_global_load_lds( \
    (const __attribute__((address_space(1))) u32*)(g), \
    (__attribute__((address_space(3))) u32*)(l), 16, 0, 0)

// ---------- fused pre: pad/transpose x -> NHWC bf16, weight transform, stats zero ----------
extern "C" __global__ void __launch_bounds__(256)
pre_kernel(const float* __restrict__ x, const float* __restrict__ wgt,
           u16* __restrict__ xp, u16* __restrict__ wt, float* __restrict__ stats)
{
    const int b   = blockIdx.x;
    const int tid = threadIdx.x;

    if (b >= PAD_BLOCKS) {
        // ---- weight transform: wgt (Cout,Cin,3,3) f32 -> wt[tap][cout][cin] bf16 ----
        const int e   = (b - PAD_BLOCKS) * 256 + tid;
        const int ci  = e & 127;
        const int t2  = e >> 7;
        const int co  = t2 & 255;
        const int tap = t2 >> 8;
        __hip_bfloat16 bv = __float2bfloat16(wgt[co * 1152 + ci * 9 + tap]);
        wt[e] = *(u16*)&bv;
        if (b == PAD_BLOCKS) {          // zero the stats buffer (ws is poisoned each call)
            stats[tid] = 0.f;
            stats[tid + 256] = 0.f;
        }
        return;
    }

    // ---- pad + transpose one (n, hp) row ----
    const int n  = b / PW_;
    const int hp = b - n * PW_;
    u16* rowp = xp + (n * PW_ + hp) * PW_ * CIN_;

    if (hp == 0 || hp == PW_ - 1) {
        #pragma unroll
        for (int k = 0; k < 4; ++k) {
            const int j = tid + k * 256;
            if (j < PW_ * CIN_ / 8)
                *(v8s*)&rowp[j * 8] = (v8s){0,0,0,0,0,0,0,0};
        }
        return;
    }

    __shared__ float tile[CIN_ * 58];   // [c][w], stride 58
    const float* xrow = x + n * CIN_ * HW_ + (hp - 1) * W_;
    for (int idx = tid; idx < CIN_ * 14; idx += 256) {    // float4 coalesced loads
        const int c  = idx / 14;
        const int w4 = idx - c * 14;
        const float4 v = *(const float4*)&xrow[c * HW_ + w4 * 4];
        float* tp = &tile[c * 58 + w4 * 4];
        tp[0] = v.x; tp[1] = v.y; tp[2] = v.z; tp[3] = v.w;
    }
    __syncthreads();

    if (tid < 32) {                     // wp=0 and wp=57 borders
        const int wp = (tid >> 4) * (PW_ - 1);
        const int cg = tid & 15;
        *(v8s*)&rowp[wp * CIN_ + cg * 8] = (v8s){0,0,0,0,0,0,0,0};
    }
    for (int idx = tid; idx < W_ * 16; idx += 256) {      // 896 v8s chunks
        const int wp = (idx >> 4) + 1;
        const int cg = idx & 15;
        v8s v;
        #pragma unroll
        for (int j = 0; j < 8; ++j) {
            __hip_bfloat16 bv = __float2bfloat16(tile[(cg * 8 + j) * 58 + (wp - 1)]);
            v[j] = *(short*)&bv;
        }
        *(v8s*)&rowp[wp * CIN_ + cg * 8] = v;
    }
}

// ====== conv: implicit GEMM 256x256 tile, BK=64, 8 waves, dbuf, barrier-guarded staging ======
#define STAGE(P, XOFF, WOFF) {                                                 \
    u16* ap_ = As + (P) * 16384;                                               \
    u16* bp_ = Bs + (P) * 16384;                                               \
    _Pragma("unroll")                                                          \
    for (int i_ = 0; i_ < 4; ++i_) {                                           \
        GLOAD16(xp + xa[i_] + (XOFF), ap_ + (i_ * 64 + wid * 8) * 64);         \
        GLOAD16(wt + wb[i_] + (WOFF), bp_ + (i_ * 64 + wid * 8) * 64);         \
    } }

#define ITER(P, STG, XOFF, WOFF) {                                             \
    const u16* ab_ = As + (P) * 16384;                                         \
    const u16* bb_ = Bs + (P) * 16384;                                         \
    v8s af_[8], bf_[4];                                                        \
    _Pragma("unroll")                                                          \
    for (int mf = 0; mf < 8; ++mf) af_[mf] = *(const v8s*)(ab_ + arow[mf] + ck0); \
    _Pragma("unroll")                                                          \
    for (int nf = 0; nf < 4; ++nf) bf_[nf] = *(const v8s*)(bb_ + brow[nf] + ck0); \
    _Pragma("unroll")                                                          \
    for (int mf = 0; mf < 8; ++mf)                                             \
        _Pragma("unroll")                                                      \
        for (int nf = 0; nf < 4; ++nf)                                         \
            acc[mf][nf] = __builtin_amdgcn_mfma_f32_16x16x32_bf16(             \
                af_[mf], bf_[nf], acc[mf][nf], 0, 0, 0);                       \
    v8s ag_[8], bg_[4];                                                        \
    _Pragma("unroll")                                                          \
    for (int mf = 0; mf < 8; ++mf) ag_[mf] = *(const v8s*)(ab_ + arow[mf] + ck1); \
    _Pragma("unroll")                                                          \
    for (int nf = 0; nf < 4; ++nf) bg_[nf] = *(const v8s*)(bb_ + brow[nf] + ck1); \
    __syncthreads();              /* all reads of buf P done; no vmem in flight */ \
    if (STG) { STAGE(P, XOFF, WOFF) }                                          \
    _Pragma("unroll")                                                          \
    for (int mf = 0; mf < 8; ++mf)                                             \
        _Pragma("unroll")                                                      \
        for (int nf = 0; nf < 4; ++nf)                                         \
            acc[mf][nf] = __builtin_amdgcn_mfma_f32_16x16x32_bf16(             \
                ag_[mf], bg_[nf], acc[mf][nf], 0, 0, 0);                       \
    __syncthreads();              /* drains the 8 gloads (covered by 32 MFMA) */ \
}

extern "C" __global__ void __launch_bounds__(512, 2)
conv_kernel(const u16* __restrict__ xp, const u16* __restrict__ wt,
            const float* __restrict__ bias, float* __restrict__ out,
            float* __restrict__ stats)
{
    __shared__ u16 As[2 * 16384];   // 64 KB: 2 x (256 rows x 64 k)
    __shared__ u16 Bs[2 * 16384];   // 64 KB

    const int t    = threadIdx.x;
    const int lane = t & 63;
    const int wid  = t >> 6;

    // XCD-bijective remap: 392 blocks = 8 chunks x 49
    const int bid   = blockIdx.x;
    const int mbase = ((bid & 7) * 49 + (bid >> 3)) << 8;

    // staging geometry (R2-verified swizzle involution)
    const int srow = lane >> 3;                  // == (staged LDS row) & 7
    const int swzc = ((lane & 7) ^ srow) << 3;   // pre-swizzled source chunk
    int xa[4], wb[4];
    #pragma unroll
    for (int i = 0; i < 4; ++i) {
        const int r   = i * 64 + wid * 8 + srow;  // 0..255
        const int m   = mbase + r;
        const int n0  = m / HW_;
        const int hw0 = m - n0 * HW_;
        const int h0  = hw0 / W_;
        const int w0  = hw0 - h0 * W_;
        xa[i] = ((n0 * PW_ + h0) * PW_ + w0) * CIN_ + swzc;
        wb[i] = r * CIN_ + swzc;                  // r == cout row
    }

    // fragment-read geometry
    const int wr = wid >> 2, wc = wid & 3;        // 2M x 4N waves; per-wave 128x64
    const int frow = lane & 15;
    const int kg   = lane >> 4;
    const int ck0  = ((kg)     ^ (frow & 7)) << 3;
    const int ck1  = ((4 | kg) ^ (frow & 7)) << 3;
    int arow[8], brow[4];
    #pragma unroll
    for (int mf = 0; mf < 8; ++mf) arow[mf] = (wr * 128 + mf * 16 + frow) * 64;
    #pragma unroll
    for (int nf = 0; nf < 4; ++nf) brow[nf] = (wc * 64 + nf * 16 + frow) * 64;

    f32x4 acc[8][4];
    #pragma unroll
    for (int i = 0; i < 8; ++i)
        #pragma unroll
        for (int j = 0; j < 4; ++j) acc[i][j] = (f32x4){0.f, 0.f, 0.f, 0.f};

    // prologue: K-tile 0 (tap0,half0) -> buf0; K-tile 1 (tap0,half1) -> buf1
    STAGE(0, 0, 0);
    STAGE(1, 64, 64);
    __syncthreads();

    #pragma unroll 1
    for (int tt = 0; tt < 8; ++tt) {              // K-tiles 0..15, staging 2..17
        const int tap = tt + 1;
        const int kh  = (tap * 11) >> 5;
        const int kw  = tap - kh * 3;
        const int xo  = (kh * PW_ + kw) * CIN_;
        const int wo  = tap * (COUT_ * CIN_);
        ITER(0, 1, xo, wo);                       // t=2tt   stages tap,half0 -> buf0
        ITER(1, 1, xo + 64, wo + 64);             // t=2tt+1 stages tap,half1 -> buf1
    }
    ITER(0, 0, 0, 0);                             // t=16
    ITER(1, 0, 0, 0);                             // t=17

    // epilogue: bias + store fp32 NCHW + fused channel sum/sumsq (verified layout)
    const int lgrp = lane >> 4;
    #pragma unroll
    for (int nf = 0; nf < 4; ++nf) {
        const int co = wc * 64 + nf * 16 + frow;       // C/D col = lane&15
        const float bv = bias[co];
        float s = 0.f, q = 0.f;
        #pragma unroll
        for (int mf = 0; mf < 8; ++mf) {
            const int mloc = wr * 128 + mf * 16 + lgrp * 4;  // C/D row = (lane>>4)*4+i
            const int mg2  = mbase + mloc;
            const int n2   = mg2 / HW_;
            const int hw2  = mg2 - n2 * HW_;
            float4 ov; float vx;
            vx = acc[mf][nf][0] + bv; ov.x = vx; s += vx; q += vx * vx;
            vx = acc[mf][nf][1] + bv; ov.y = vx; s += vx; q += vx * vx;
            vx = acc[mf][nf][2] + bv; ov.z = vx; s += vx; q += vx * vx;
            vx = acc[mf][nf][3] + bv; ov.w = vx; s += vx; q += vx * vx;
            *(float4*)(out + (n2 * COUT_ + co) * HW_ + hw2) = ov;
        }
        s += __shfl_xor(s, 16); s += __shfl_xor(s, 32);
        q += __shfl_xor(q, 16); q += __shfl_xor(q, 32);
        if (lgrp == 0) {
            atomicAdd(&stats[co], s);
            atomicAdd(&stats[COUT_ + co], q);
        }
    }
}

// ---------------- BN(training) + ReLU, in place on d_out ----------------
extern "C" __global__ void bn_kernel(float* __restrict__ y, const float* __restrict__ stats,
                                     const float* __restrict__ gamma, const float* __restrict__ beta)
{
    const int i4 = blockIdx.x * 256 + threadIdx.x;
    const int e  = i4 * 4;
    const int co = (e / HW_) & (COUT_ - 1);
    const float inv  = 1.f / KCNT;
    const float mean = stats[co] * inv;
    const float var  = stats[COUT_ + co] * inv - mean * mean;
    const float scale = gamma[co] * rsqrtf(var + 1e-5f);
    const float shift = beta[co] - mean * scale;
    float4 v = *(float4*)(y + e);
    v.x = fmaxf(fmaf(v.x, scale, shift), 0.f);
    v.y = fmaxf(fmaf(v.y, scale, shift), 0.f);
    v.z = fmaxf(fmaf(v.z, scale, shift), 0.f);
    v.w = fmaxf(fmaf(v.w, scale, shift), 0.f);
    *(float4*)(y + e) = v;
}

extern "C" void kernel_launch(void* const* d_in, const int* in_sizes, int n_in,
                              void* d_out, int out_size, void* d_ws, size_t ws_size,
                              hipStream_t stream)
{
    const float* x     = (const float*)d_in[0];
    const float* wgt   = (const float*)d_in[1];
    const float* bias  = (const float*)d_in[2];
    const float* gamma = (const float*)d_in[3];
    const float* beta  = (const float*)d_in[4];
    float* out = (float*)d_out;

    char* ws = (char*)d_ws;
    u16*   xp    = (u16*)ws;
    u16*   wt    = (u16*)(ws + WT_OFFB);
    float* stats = (float*)(ws + ST_OFFB);

    pre_kernel<<<PAD_BLOCKS + WT_BLOCKS, 256, 0, stream>>>(x, wgt, xp, wt, stats);
    conv_kernel<<<392, 512, 0, stream>>>(xp, wt, bias, out, stats);
    bn_kernel<<<(out_size / 4) / 256, 256, 0, stream>>>(out, stats, gamma, beta);
}